// Round 1
// baseline (622.059 us; speedup 1.0000x reference)
//
#include <hip/hip_runtime.h>
#include <math.h>

// Problem constants (fixed by the reference)
#define NN 50000
#define EE 800000
#define DIN 256
#define HID 64
#define NHEAD 2
#define NCLS 64
#define NEG_SLOPE 0.01f

// ---------------------------------------------------------------------------
// CSR build: histogram of dst, exclusive scan, scatter src into per-dst lists
// ---------------------------------------------------------------------------
__global__ __launch_bounds__(256) void hist_kernel(const int* __restrict__ dst,
                                                   int* __restrict__ cnt, int E) {
    int e = blockIdx.x * 256 + threadIdx.x;
    if (e < E) atomicAdd(&cnt[dst[e]], 1);
}

__global__ __launch_bounds__(1024) void scan_kernel(const int* __restrict__ cnt,
                                                    int* __restrict__ off, int Nn) {
    __shared__ int wsums[16];
    __shared__ int carry;
    int tid = threadIdx.x, lane = tid & 63, w = tid >> 6;
    if (tid == 0) { carry = 0; off[0] = 0; }
    __syncthreads();
    for (int base = 0; base < Nn; base += 1024) {
        int i = base + tid;
        int v = (i < Nn) ? cnt[i] : 0;
        int x = v;
#pragma unroll
        for (int d = 1; d < 64; d <<= 1) {
            int y = __shfl_up(x, d);
            if (lane >= d) x += y;
        }
        if (lane == 63) wsums[w] = x;
        __syncthreads();
        if (w == 0 && lane < 16) {
            int ws = wsums[lane];
#pragma unroll
            for (int d = 1; d < 16; d <<= 1) {
                int y = __shfl_up(ws, d);
                if (lane >= d) ws += y;
            }
            wsums[lane] = ws;
        }
        __syncthreads();
        int woff = (w > 0) ? wsums[w - 1] : 0;
        int incl = carry + woff + x;
        if (i < Nn) off[i + 1] = incl;
        __syncthreads();
        if (tid == 1023) carry = incl;
        __syncthreads();
    }
}

__global__ __launch_bounds__(256) void scatter_kernel(const int* __restrict__ src,
                                                      const int* __restrict__ dst,
                                                      const int* __restrict__ off,
                                                      int* __restrict__ cnt,
                                                      int* __restrict__ esrc, int E) {
    int e = blockIdx.x * 256 + threadIdx.x;
    if (e >= E) return;
    int d = dst[e];
    int pos = atomicAdd(&cnt[d], 1);
    esrc[off[d] + pos] = src[e];
}

// ---------------------------------------------------------------------------
// Dense: ft[n, h*64 + k] = sum_d x[n,d] * W[h,d,k] + b[h,k]
// grid = (ceil(N/128), H); block = 256; thread computes 8 rows x 4 cols
// ---------------------------------------------------------------------------
__global__ __launch_bounds__(256) void gemm_kernel(const float* __restrict__ X,
                                                   const float* __restrict__ W,
                                                   const float* __restrict__ bias,
                                                   float* __restrict__ FT,
                                                   int Nn, int D) {
    const int TM = 128, KT = 32;
    __shared__ float Xs[TM][KT + 1];   // pad -> conflict-free column reads
    __shared__ float Ws[KT][64];
    int tid = threadIdx.x;
    int h = blockIdx.y;
    int HK = gridDim.y * 64;
    int n0 = blockIdx.x * TM;
    int tx = tid & 15, ty = tid >> 4;

    float acc[8][4];
#pragma unroll
    for (int i = 0; i < 8; i++)
#pragma unroll
        for (int j = 0; j < 4; j++) acc[i][j] = 0.f;

    const float* Wh = W + (size_t)h * D * 64;

    for (int d0 = 0; d0 < D; d0 += KT) {
        // stage X tile: 128 x 32 floats = 1024 float4
#pragma unroll
        for (int l = 0; l < 4; l++) {
            int idx = tid + l * 256;
            int row = idx >> 3, c4 = idx & 7;
            float4 v = make_float4(0.f, 0.f, 0.f, 0.f);
            if (n0 + row < Nn)
                v = *(const float4*)&X[(size_t)(n0 + row) * D + d0 + c4 * 4];
            Xs[row][c4 * 4 + 0] = v.x;
            Xs[row][c4 * 4 + 1] = v.y;
            Xs[row][c4 * 4 + 2] = v.z;
            Xs[row][c4 * 4 + 3] = v.w;
        }
        // stage W tile: 32 x 64 floats = 512 float4
#pragma unroll
        for (int l = 0; l < 2; l++) {
            int idx = tid + l * 256;
            int kk = idx >> 4, c4 = idx & 15;
            float4 v = *(const float4*)&Wh[(size_t)(d0 + kk) * 64 + c4 * 4];
            Ws[kk][c4 * 4 + 0] = v.x;
            Ws[kk][c4 * 4 + 1] = v.y;
            Ws[kk][c4 * 4 + 2] = v.z;
            Ws[kk][c4 * 4 + 3] = v.w;
        }
        __syncthreads();
#pragma unroll
        for (int kk = 0; kk < KT; kk++) {
            float xr[8];
#pragma unroll
            for (int i = 0; i < 8; i++) xr[i] = Xs[ty * 8 + i][kk];
            float wv[4];
#pragma unroll
            for (int j = 0; j < 4; j++) wv[j] = Ws[kk][tx * 4 + j];
#pragma unroll
            for (int i = 0; i < 8; i++)
#pragma unroll
                for (int j = 0; j < 4; j++) acc[i][j] += xr[i] * wv[j];
        }
        __syncthreads();
    }

    float bj[4];
#pragma unroll
    for (int j = 0; j < 4; j++) bj[j] = bias[h * 64 + tx * 4 + j];
#pragma unroll
    for (int i = 0; i < 8; i++) {
        int n = n0 + ty * 8 + i;
        if (n < Nn) {
            float4 o;
            o.x = acc[i][0] + bj[0];
            o.y = acc[i][1] + bj[1];
            o.z = acc[i][2] + bj[2];
            o.w = acc[i][3] + bj[3];
            *(float4*)&FT[(size_t)n * HK + h * 64 + tx * 4] = o;
        }
    }
}

// ---------------------------------------------------------------------------
// a1[n,h] = ft[n,h,:] . al[h,:] + bl[h];  a2 likewise with ar/br
// one wave per (n,h)
// ---------------------------------------------------------------------------
__global__ __launch_bounds__(256) void attn_kernel(const float* __restrict__ ft,
                                                   const float* __restrict__ al,
                                                   const float* __restrict__ bl,
                                                   const float* __restrict__ ar,
                                                   const float* __restrict__ br,
                                                   float* __restrict__ a1,
                                                   float* __restrict__ a2,
                                                   int NH, int H) {
    int wid = (blockIdx.x * 256 + threadIdx.x) >> 6;
    int lane = threadIdx.x & 63;
    if (wid >= NH) return;
    int h = wid % H;
    float v = ft[(size_t)wid * 64 + lane];
    float r1 = v * al[h * 64 + lane];
    float r2 = v * ar[h * 64 + lane];
#pragma unroll
    for (int d = 32; d > 0; d >>= 1) {
        r1 += __shfl_xor(r1, d);
        r2 += __shfl_xor(r2, d);
    }
    if (lane == 0) {
        a1[wid] = r1 + bl[h];
        a2[wid] = r2 + br[h];
    }
}

// ---------------------------------------------------------------------------
// Edge softmax + aggregation + ELU. One block per dst node.
// block = H*64 threads; thread owns output element (h = tid/64, k = tid%64).
// ---------------------------------------------------------------------------
template <int H>
__global__ __launch_bounds__(64 * H) void edge_agg_kernel(const float* __restrict__ ft,
                                                          const float* __restrict__ a1,
                                                          const float* __restrict__ a2,
                                                          const int* __restrict__ off,
                                                          const int* __restrict__ esrc,
                                                          float* __restrict__ out) {
    const int BS = 64 * H;
    const int CH = 256;
    int n = blockIdx.x, tid = threadIdx.x;
    int o0 = off[n];
    int deg = off[n + 1] - o0;
    int h = tid >> 6;
    if (deg == 0) {
        out[(size_t)n * BS + tid] = 0.f;  // elu(0) = 0
        return;
    }
    __shared__ float red[BS];
    __shared__ float s_m[H], s_d[H];
    __shared__ float wbuf[CH * H];
    __shared__ int sbuf[CH];

    const int hh = tid % H;  // phase-role head (fixed per thread since H | BS)
    const float a1v = a1[(size_t)n * H + hh];

    // phase 1: per-head max of s
    float lm = -1e30f;
    for (int i = tid; i < deg * H; i += BS) {
        int e = i / H;
        int sj = esrc[o0 + e];
        float s = a1v + a2[(size_t)sj * H + hh];
        s = s > 0.f ? s : NEG_SLOPE * s;
        lm = fmaxf(lm, s);
    }
    red[tid] = lm;
    __syncthreads();
    for (int st = BS / 2; st >= H; st >>= 1) {
        if (tid < st) red[tid] = fmaxf(red[tid], red[tid + st]);
        __syncthreads();
    }
    if (tid < H) s_m[tid] = red[tid];
    __syncthreads();

    // phase 2: per-head sum of exp(s - m)
    float mh = s_m[hh];
    float ld = 0.f;
    for (int i = tid; i < deg * H; i += BS) {
        int e = i / H;
        int sj = esrc[o0 + e];
        float s = a1v + a2[(size_t)sj * H + hh];
        s = s > 0.f ? s : NEG_SLOPE * s;
        ld += __expf(s - mh);
    }
    red[tid] = ld;
    __syncthreads();
    for (int st = BS / 2; st >= H; st >>= 1) {
        if (tid < st) red[tid] += red[tid + st];
        __syncthreads();
    }
    if (tid < H) s_d[tid] = red[tid];
    __syncthreads();

    // phase 3: acc = sum_e exp(s_e - m) * ft[src_e, h, k], then /denom, elu
    float acc = 0.f;
    for (int c0 = 0; c0 < deg; c0 += CH) {
        int nE = min(CH, deg - c0);
        __syncthreads();  // protect wbuf/sbuf reuse across chunks
        for (int i = tid; i < nE * H; i += BS) {
            int e = c0 + i / H;
            int sj = esrc[o0 + e];
            float s = a1v + a2[(size_t)sj * H + hh];
            s = s > 0.f ? s : NEG_SLOPE * s;
            wbuf[i] = __expf(s - mh);
            if (hh == 0) sbuf[i / H] = sj;
        }
        __syncthreads();
        for (int j = 0; j < nE; j++) {
            float w = wbuf[j * H + h];
            int sj = sbuf[j];
            acc += w * ft[(size_t)sj * BS + tid];
        }
    }
    float res = acc / s_d[h];
    out[(size_t)n * BS + tid] = res > 0.f ? res : expm1f(res);
}

// ---------------------------------------------------------------------------
// launch
// ---------------------------------------------------------------------------
extern "C" void kernel_launch(void* const* d_in, const int* in_sizes, int n_in,
                              void* d_out, int out_size, void* d_ws, size_t ws_size,
                              hipStream_t stream) {
    const float* features = (const float*)d_in[0];
    const int* src = (const int*)d_in[1];
    const int* dst = (const int*)d_in[2];
    const float* W0 = (const float*)d_in[3];
    const float* b0 = (const float*)d_in[4];
    const float* al0 = (const float*)d_in[5];
    const float* bl0 = (const float*)d_in[6];
    const float* ar0 = (const float*)d_in[7];
    const float* br0 = (const float*)d_in[8];
    const float* W1 = (const float*)d_in[9];
    const float* b1 = (const float*)d_in[10];
    const float* al1 = (const float*)d_in[11];
    const float* bl1 = (const float*)d_in[12];
    const float* ar1 = (const float*)d_in[13];
    const float* br1 = (const float*)d_in[14];
    const float* Wf = (const float*)d_in[15];
    const float* bf = (const float*)d_in[16];
    const float* alf = (const float*)d_in[17];
    const float* blf = (const float*)d_in[18];
    const float* arf = (const float*)d_in[19];
    const float* brf = (const float*)d_in[20];

    // workspace carve (all 256B-aligned)
    char* p = (char*)d_ws;
    auto carve = [&](size_t bytes) {
        void* q = (void*)p;
        p += (bytes + 255) & ~(size_t)255;
        return q;
    };
    float* ft = (float*)carve((size_t)NN * 128 * 4);
    float* xbuf = (float*)carve((size_t)NN * 128 * 4);
    float* a1 = (float*)carve((size_t)NN * 2 * 4);
    float* a2 = (float*)carve((size_t)NN * 2 * 4);
    int* off = (int*)carve((size_t)(NN + 1) * 4);
    int* cnt = (int*)carve((size_t)NN * 4);
    int* esrc = (int*)carve((size_t)EE * 4);

    // ---- CSR build (dst-sorted adjacency) ----
    hipMemsetAsync(cnt, 0, (size_t)NN * 4, stream);
    hist_kernel<<<(EE + 255) / 256, 256, 0, stream>>>(dst, cnt, EE);
    scan_kernel<<<1, 1024, 0, stream>>>(cnt, off, NN);
    hipMemsetAsync(cnt, 0, (size_t)NN * 4, stream);
    scatter_kernel<<<(EE + 255) / 256, 256, 0, stream>>>(src, dst, off, cnt, esrc, EE);

    const int gx = (NN + 127) / 128;

    // ---- layer 0: D=256, H=2 ----
    gemm_kernel<<<dim3(gx, 2), 256, 0, stream>>>(features, W0, b0, ft, NN, DIN);
    attn_kernel<<<(NN * 2 * 64 + 255) / 256, 256, 0, stream>>>(ft, al0, bl0, ar0, br0,
                                                               a1, a2, NN * 2, 2);
    edge_agg_kernel<2><<<NN, 128, 0, stream>>>(ft, a1, a2, off, esrc, xbuf);

    // ---- layer 1: D=128, H=2 ----
    gemm_kernel<<<dim3(gx, 2), 256, 0, stream>>>(xbuf, W1, b1, ft, NN, 128);
    attn_kernel<<<(NN * 2 * 64 + 255) / 256, 256, 0, stream>>>(ft, al1, bl1, ar1, br1,
                                                               a1, a2, NN * 2, 2);
    edge_agg_kernel<2><<<NN, 128, 0, stream>>>(ft, a1, a2, off, esrc, xbuf);

    // ---- final layer: D=128, H=1, writes d_out ----
    gemm_kernel<<<dim3(gx, 1), 256, 0, stream>>>(xbuf, Wf, bf, ft, NN, 128);
    attn_kernel<<<(NN * 1 * 64 + 255) / 256, 256, 0, stream>>>(ft, alf, blf, arf, brf,
                                                               a1, a2, NN * 1, 1);
    edge_agg_kernel<1><<<NN, 64, 0, stream>>>(ft, a1, a2, off, esrc, (float*)d_out);
}

// Round 2
// 485.897 us; speedup vs baseline: 1.2802x; 1.2802x over previous
//
#include <hip/hip_runtime.h>
#include <math.h>

// Problem constants (fixed by the reference)
#define NN 50000
#define EE 800000
#define DIN 256
#define NEG_SLOPE 0.01f

// ---------------------------------------------------------------------------
// CSR build: histogram of dst, parallel scan, scatter src into per-dst lists
// ---------------------------------------------------------------------------
__global__ __launch_bounds__(256) void hist_kernel(const int* __restrict__ dst,
                                                   int* __restrict__ cnt, int E) {
    int e = blockIdx.x * 256 + threadIdx.x;
    if (e < E) atomicAdd(&cnt[dst[e]], 1);
}

// per-block inclusive scan of cnt into off[i+1] (no global prefix yet);
// writes block total to aux[b]; zeroes cnt for the scatter pass.
__global__ __launch_bounds__(1024) void scanA_kernel(int* __restrict__ cnt,
                                                     int* __restrict__ off,
                                                     int* __restrict__ aux, int Nn) {
    __shared__ int wsums[16];
    int tid = threadIdx.x, lane = tid & 63, w = tid >> 6;
    int i = blockIdx.x * 1024 + tid;
    int v = (i < Nn) ? cnt[i] : 0;
    if (i < Nn) cnt[i] = 0;
    int x = v;
#pragma unroll
    for (int d = 1; d < 64; d <<= 1) {
        int y = __shfl_up(x, d);
        if (lane >= d) x += y;
    }
    if (lane == 63) wsums[w] = x;
    __syncthreads();
    if (w == 0 && lane < 16) {
        int ws = wsums[lane];
#pragma unroll
        for (int d = 1; d < 16; d <<= 1) {
            int y = __shfl_up(ws, d);
            if (lane >= d) ws += y;
        }
        wsums[lane] = ws;
    }
    __syncthreads();
    int incl = x + (w > 0 ? wsums[w - 1] : 0);
    if (i < Nn) off[i + 1] = incl;
    if (tid == 1023) aux[blockIdx.x] = incl;
}

// add cross-block prefix
__global__ __launch_bounds__(1024) void scanC_kernel(const int* __restrict__ aux,
                                                     int* __restrict__ off, int Nn) {
    int b = blockIdx.x;
    int prefix = 0;
    for (int j = 0; j < b; j++) prefix += aux[j];  // uniform -> scalar loads, L2-hot
    int i = b * 1024 + threadIdx.x;
    if (i < Nn) off[i + 1] += prefix;
    if (i == 0 && b == 0) off[0] = 0;
}

__global__ __launch_bounds__(256) void scatter_kernel(const int* __restrict__ src,
                                                      const int* __restrict__ dst,
                                                      const int* __restrict__ off,
                                                      int* __restrict__ cnt,
                                                      int* __restrict__ esrc, int E) {
    int e = blockIdx.x * 256 + threadIdx.x;
    if (e >= E) return;
    int d = dst[e];
    int pos = atomicAdd(&cnt[d], 1);
    esrc[off[d] + pos] = src[e];
}

// ---------------------------------------------------------------------------
// Dense + fused attention dots:
//   ft[n, h*64+k] = sum_d x[n,d]*W[h,d,k] + b[h,k]
//   a1[n,h] = ft[n,h,:].al[h,:] + bl[h];  a2 likewise (ar,br)
// grid = (ceil(N/128), H); block = 256; thread computes 8 rows x 4 cols
// ---------------------------------------------------------------------------
__global__ __launch_bounds__(256) void gemm_attn_kernel(
    const float* __restrict__ X, const float* __restrict__ W,
    const float* __restrict__ bias, const float* __restrict__ al,
    const float* __restrict__ bl, const float* __restrict__ ar,
    const float* __restrict__ br, float* __restrict__ FT,
    float* __restrict__ A1, float* __restrict__ A2, int Nn, int D) {
    const int TM = 128, KT = 32;
    __shared__ float Xs[TM][KT + 1];
    __shared__ float Ws[KT][64];
    int tid = threadIdx.x;
    int h = blockIdx.y;
    int H = gridDim.y;
    int HK = H * 64;
    int n0 = blockIdx.x * TM;
    int tx = tid & 15, ty = tid >> 4;

    float acc[8][4];
#pragma unroll
    for (int i = 0; i < 8; i++)
#pragma unroll
        for (int j = 0; j < 4; j++) acc[i][j] = 0.f;

    const float* Wh = W + (size_t)h * D * 64;

    for (int d0 = 0; d0 < D; d0 += KT) {
#pragma unroll
        for (int l = 0; l < 4; l++) {
            int idx = tid + l * 256;
            int row = idx >> 3, c4 = idx & 7;
            float4 v = make_float4(0.f, 0.f, 0.f, 0.f);
            if (n0 + row < Nn)
                v = *(const float4*)&X[(size_t)(n0 + row) * D + d0 + c4 * 4];
            Xs[row][c4 * 4 + 0] = v.x;
            Xs[row][c4 * 4 + 1] = v.y;
            Xs[row][c4 * 4 + 2] = v.z;
            Xs[row][c4 * 4 + 3] = v.w;
        }
#pragma unroll
        for (int l = 0; l < 2; l++) {
            int idx = tid + l * 256;
            int kk = idx >> 4, c4 = idx & 15;
            float4 v = *(const float4*)&Wh[(size_t)(d0 + kk) * 64 + c4 * 4];
            Ws[kk][c4 * 4 + 0] = v.x;
            Ws[kk][c4 * 4 + 1] = v.y;
            Ws[kk][c4 * 4 + 2] = v.z;
            Ws[kk][c4 * 4 + 3] = v.w;
        }
        __syncthreads();
#pragma unroll
        for (int kk = 0; kk < KT; kk++) {
            float xr[8];
#pragma unroll
            for (int i = 0; i < 8; i++) xr[i] = Xs[ty * 8 + i][kk];
            float wv[4];
#pragma unroll
            for (int j = 0; j < 4; j++) wv[j] = Ws[kk][tx * 4 + j];
#pragma unroll
            for (int i = 0; i < 8; i++)
#pragma unroll
                for (int j = 0; j < 4; j++) acc[i][j] += xr[i] * wv[j];
        }
        __syncthreads();
    }

    float bj[4], alj[4], arj[4];
#pragma unroll
    for (int j = 0; j < 4; j++) {
        bj[j] = bias[h * 64 + tx * 4 + j];
        alj[j] = al[h * 64 + tx * 4 + j];
        arj[j] = ar[h * 64 + tx * 4 + j];
    }
    float blh = bl[h], brh = br[h];
#pragma unroll
    for (int i = 0; i < 8; i++) {
        int n = n0 + ty * 8 + i;
        float4 o;
        o.x = acc[i][0] + bj[0];
        o.y = acc[i][1] + bj[1];
        o.z = acc[i][2] + bj[2];
        o.w = acc[i][3] + bj[3];
        float r1 = o.x * alj[0] + o.y * alj[1] + o.z * alj[2] + o.w * alj[3];
        float r2 = o.x * arj[0] + o.y * arj[1] + o.z * arj[2] + o.w * arj[3];
#pragma unroll
        for (int d = 1; d < 16; d <<= 1) {  // reduce across the 16 tx lanes
            r1 += __shfl_xor(r1, d);
            r2 += __shfl_xor(r2, d);
        }
        if (n < Nn) {
            *(float4*)&FT[(size_t)n * HK + h * 64 + tx * 4] = o;
            if (tx == 0) {
                A1[(size_t)n * H + h] = r1 + blh;
                A2[(size_t)n * H + h] = r2 + brh;
            }
        }
    }
}

// ---------------------------------------------------------------------------
// Edge softmax + aggregation + ELU, one WAVE per dst node, single pass
// (online softmax), wave-synchronous (no barriers). H=2: lane owns output
// elems 2*lane, 2*lane+1 (both in head lane>>5).
// ---------------------------------------------------------------------------
__global__ __launch_bounds__(256) void edge_agg2_kernel(
    const float* __restrict__ ft, const float* __restrict__ a1,
    const float* __restrict__ a2, const int* __restrict__ off,
    const int* __restrict__ esrc, float* __restrict__ out, int Nn) {
    __shared__ __align__(16) float ws[4][64];  // [wave][h*32 + e]
    __shared__ __align__(16) int sjs[4][32];
    int wv = threadIdx.x >> 6, lane = threadIdx.x & 63;
    int n = blockIdx.x * 4 + wv;
    if (n >= Nn) return;
    int o0 = off[n], deg = off[n + 1] - o0;
    int hs = lane >> 5;   // head this lane scores AND outputs
    int el = lane & 31;   // edge slot within chunk
    if (deg == 0) {
        *(float2*)&out[(size_t)n * 128 + lane * 2] = make_float2(0.f, 0.f);
        return;
    }
    float a1v = a1[(size_t)n * 2 + hs];
    float m = -1e30f, dsum = 0.f;
    float accx = 0.f, accy = 0.f;
    for (int e0 = 0; e0 < deg; e0 += 32) {
        int nE = min(32, deg - e0);
        int sj = 0;
        float s = -1e30f;
        if (el < nE) {
            sj = esrc[o0 + e0 + el];
            float t = a1v + a2[(size_t)sj * 2 + hs];
            s = t > 0.f ? t : NEG_SLOPE * t;
        }
        float cm = s;
#pragma unroll
        for (int d = 1; d < 32; d <<= 1) cm = fmaxf(cm, __shfl_xor(cm, d));
        float nm = fmaxf(m, cm);
        float scale = __expf(m - nm);
        float wgt = (el < nE) ? __expf(s - nm) : 0.f;
        float csum = wgt;
#pragma unroll
        for (int d = 1; d < 32; d <<= 1) csum += __shfl_xor(csum, d);
        dsum = dsum * scale + csum;
        accx *= scale;
        accy *= scale;
        m = nm;
        ws[wv][hs * 32 + el] = wgt;
        if (hs == 0 && el < nE) sjs[wv][el] = sj;
        // DS ops within a wave execute in order -> no barrier needed.
        int j = 0;
        for (; j + 4 <= nE; j += 4) {
            float4 w4 = *(const float4*)&ws[wv][hs * 32 + j];
            int4 s4 = *(const int4*)&sjs[wv][j];
            float2 f0 = *(const float2*)&ft[(size_t)s4.x * 128 + lane * 2];
            float2 f1 = *(const float2*)&ft[(size_t)s4.y * 128 + lane * 2];
            float2 f2 = *(const float2*)&ft[(size_t)s4.z * 128 + lane * 2];
            float2 f3 = *(const float2*)&ft[(size_t)s4.w * 128 + lane * 2];
            accx += w4.x * f0.x + w4.y * f1.x + w4.z * f2.x + w4.w * f3.x;
            accy += w4.x * f0.y + w4.y * f1.y + w4.z * f2.y + w4.w * f3.y;
        }
        for (; j < nE; j++) {
            float w0 = ws[wv][hs * 32 + j];
            int s0 = sjs[wv][j];
            float2 f0 = *(const float2*)&ft[(size_t)s0 * 128 + lane * 2];
            accx += w0 * f0.x;
            accy += w0 * f0.y;
        }
    }
    float rd = 1.f / dsum;
    float rx = accx * rd, ry = accy * rd;
    rx = rx > 0.f ? rx : expm1f(rx);
    ry = ry > 0.f ? ry : expm1f(ry);
    *(float2*)&out[(size_t)n * 128 + lane * 2] = make_float2(rx, ry);
}

// H=1 variant: lane owns output elem `lane`; chunks of 64 edges.
__global__ __launch_bounds__(256) void edge_agg1_kernel(
    const float* __restrict__ ft, const float* __restrict__ a1,
    const float* __restrict__ a2, const int* __restrict__ off,
    const int* __restrict__ esrc, float* __restrict__ out, int Nn) {
    __shared__ __align__(16) float ws[4][64];
    __shared__ __align__(16) int sjs[4][64];
    int wv = threadIdx.x >> 6, lane = threadIdx.x & 63;
    int n = blockIdx.x * 4 + wv;
    if (n >= Nn) return;
    int o0 = off[n], deg = off[n + 1] - o0;
    if (deg == 0) {
        out[(size_t)n * 64 + lane] = 0.f;
        return;
    }
    float a1v = a1[n];
    float m = -1e30f, dsum = 0.f, acc = 0.f;
    for (int e0 = 0; e0 < deg; e0 += 64) {
        int nE = min(64, deg - e0);
        int sj = 0;
        float s = -1e30f;
        if (lane < nE) {
            sj = esrc[o0 + e0 + lane];
            float t = a1v + a2[sj];
            s = t > 0.f ? t : NEG_SLOPE * t;
        }
        float cm = s;
#pragma unroll
        for (int d = 1; d < 64; d <<= 1) cm = fmaxf(cm, __shfl_xor(cm, d));
        float nm = fmaxf(m, cm);
        float scale = __expf(m - nm);
        float wgt = (lane < nE) ? __expf(s - nm) : 0.f;
        float csum = wgt;
#pragma unroll
        for (int d = 1; d < 64; d <<= 1) csum += __shfl_xor(csum, d);
        dsum = dsum * scale + csum;
        acc *= scale;
        m = nm;
        ws[wv][lane] = wgt;
        if (lane < nE) sjs[wv][lane] = sj;
        int j = 0;
        for (; j + 4 <= nE; j += 4) {
            float4 w4 = *(const float4*)&ws[wv][j];
            int4 s4 = *(const int4*)&sjs[wv][j];
            float f0 = ft[(size_t)s4.x * 64 + lane];
            float f1 = ft[(size_t)s4.y * 64 + lane];
            float f2 = ft[(size_t)s4.z * 64 + lane];
            float f3 = ft[(size_t)s4.w * 64 + lane];
            acc += w4.x * f0 + w4.y * f1 + w4.z * f2 + w4.w * f3;
        }
        for (; j < nE; j++) {
            acc += ws[wv][j] * ft[(size_t)sjs[wv][j] * 64 + lane];
        }
    }
    float r = acc / dsum;
    out[(size_t)n * 64 + lane] = r > 0.f ? r : expm1f(r);
}

// ---------------------------------------------------------------------------
// launch
// ---------------------------------------------------------------------------
extern "C" void kernel_launch(void* const* d_in, const int* in_sizes, int n_in,
                              void* d_out, int out_size, void* d_ws, size_t ws_size,
                              hipStream_t stream) {
    const float* features = (const float*)d_in[0];
    const int* src = (const int*)d_in[1];
    const int* dst = (const int*)d_in[2];
    const float* W0 = (const float*)d_in[3];
    const float* b0 = (const float*)d_in[4];
    const float* al0 = (const float*)d_in[5];
    const float* bl0 = (const float*)d_in[6];
    const float* ar0 = (const float*)d_in[7];
    const float* br0 = (const float*)d_in[8];
    const float* W1 = (const float*)d_in[9];
    const float* b1 = (const float*)d_in[10];
    const float* al1 = (const float*)d_in[11];
    const float* bl1 = (const float*)d_in[12];
    const float* ar1 = (const float*)d_in[13];
    const float* br1 = (const float*)d_in[14];
    const float* Wf = (const float*)d_in[15];
    const float* bf = (const float*)d_in[16];
    const float* alf = (const float*)d_in[17];
    const float* blf = (const float*)d_in[18];
    const float* arf = (const float*)d_in[19];
    const float* brf = (const float*)d_in[20];

    char* p = (char*)d_ws;
    auto carve = [&](size_t bytes) {
        void* q = (void*)p;
        p += (bytes + 255) & ~(size_t)255;
        return q;
    };
    float* ft = (float*)carve((size_t)NN * 128 * 4);
    float* xbuf = (float*)carve((size_t)NN * 128 * 4);
    float* a1 = (float*)carve((size_t)NN * 2 * 4);
    float* a2 = (float*)carve((size_t)NN * 2 * 4);
    int* off = (int*)carve((size_t)(NN + 1) * 4);
    int* cnt = (int*)carve((size_t)NN * 4);
    int* esrc = (int*)carve((size_t)EE * 4);
    int* aux = (int*)carve(64 * 4);

    const int NB_SCAN = (NN + 1023) / 1024;

    // ---- CSR build ----
    hipMemsetAsync(cnt, 0, (size_t)NN * 4, stream);
    hist_kernel<<<(EE + 255) / 256, 256, 0, stream>>>(dst, cnt, EE);
    scanA_kernel<<<NB_SCAN, 1024, 0, stream>>>(cnt, off, aux, NN);
    scanC_kernel<<<NB_SCAN, 1024, 0, stream>>>(aux, off, NN);
    scatter_kernel<<<(EE + 255) / 256, 256, 0, stream>>>(src, dst, off, cnt, esrc, EE);

    const int gx = (NN + 127) / 128;
    const int gn = (NN + 3) / 4;

    // ---- layer 0: D=256, H=2 ----
    gemm_attn_kernel<<<dim3(gx, 2), 256, 0, stream>>>(features, W0, b0, al0, bl0, ar0,
                                                      br0, ft, a1, a2, NN, DIN);
    edge_agg2_kernel<<<gn, 256, 0, stream>>>(ft, a1, a2, off, esrc, xbuf, NN);

    // ---- layer 1: D=128, H=2 ----
    gemm_attn_kernel<<<dim3(gx, 2), 256, 0, stream>>>(xbuf, W1, b1, al1, bl1, ar1, br1,
                                                      ft, a1, a2, NN, 128);
    edge_agg2_kernel<<<gn, 256, 0, stream>>>(ft, a1, a2, off, esrc, xbuf, NN);

    // ---- final layer: D=128, H=1 ----
    gemm_attn_kernel<<<dim3(gx, 1), 256, 0, stream>>>(xbuf, Wf, bf, alf, blf, arf, brf,
                                                      ft, a1, a2, NN, 128);
    edge_agg1_kernel<<<gn, 256, 0, stream>>>(ft, a1, a2, off, esrc, (float*)d_out, NN);
}

// Round 3
// 420.041 us; speedup vs baseline: 1.4809x; 1.1568x over previous
//
#include <hip/hip_runtime.h>
#include <math.h>

// Problem constants (fixed by the reference)
#define NN 50000
#define EE 800000
#define DIN 256
#define NEG_SLOPE 0.01f

typedef __attribute__((ext_vector_type(8))) short bf16x8;
typedef __attribute__((ext_vector_type(4))) float f32x4;

__device__ __forceinline__ unsigned short bf16_rne(float f) {
    unsigned int u = __float_as_uint(f);
    u += 0x7fffu + ((u >> 16) & 1u);
    return (unsigned short)(u >> 16);
}
__device__ __forceinline__ float bf16_tof(unsigned short h) {
    return __uint_as_float(((unsigned int)h) << 16);
}

// ---------------------------------------------------------------------------
// CSR build: histogram of dst, parallel scan, scatter src into per-dst lists
// ---------------------------------------------------------------------------
__global__ __launch_bounds__(256) void hist_kernel(const int* __restrict__ dst,
                                                   int* __restrict__ cnt, int E) {
    int e = blockIdx.x * 256 + threadIdx.x;
    if (e < E) atomicAdd(&cnt[dst[e]], 1);
}

__global__ __launch_bounds__(1024) void scanA_kernel(int* __restrict__ cnt,
                                                     int* __restrict__ off,
                                                     int* __restrict__ aux, int Nn) {
    __shared__ int wsums[16];
    int tid = threadIdx.x, lane = tid & 63, w = tid >> 6;
    int i = blockIdx.x * 1024 + tid;
    int v = (i < Nn) ? cnt[i] : 0;
    if (i < Nn) cnt[i] = 0;
    int x = v;
#pragma unroll
    for (int d = 1; d < 64; d <<= 1) {
        int y = __shfl_up(x, d);
        if (lane >= d) x += y;
    }
    if (lane == 63) wsums[w] = x;
    __syncthreads();
    if (w == 0 && lane < 16) {
        int ws = wsums[lane];
#pragma unroll
        for (int d = 1; d < 16; d <<= 1) {
            int y = __shfl_up(ws, d);
            if (lane >= d) ws += y;
        }
        wsums[lane] = ws;
    }
    __syncthreads();
    int incl = x + (w > 0 ? wsums[w - 1] : 0);
    if (i < Nn) off[i + 1] = incl;
    if (tid == 1023) aux[blockIdx.x] = incl;
}

__global__ __launch_bounds__(1024) void scanC_kernel(const int* __restrict__ aux,
                                                     int* __restrict__ off, int Nn) {
    int b = blockIdx.x;
    int prefix = 0;
    for (int j = 0; j < b; j++) prefix += aux[j];
    int i = b * 1024 + threadIdx.x;
    if (i < Nn) off[i + 1] += prefix;
    if (i == 0 && b == 0) off[0] = 0;
}

__global__ __launch_bounds__(256) void scatter_kernel(const int* __restrict__ src,
                                                      const int* __restrict__ dst,
                                                      const int* __restrict__ off,
                                                      int* __restrict__ cnt,
                                                      int* __restrict__ esrc, int E) {
    int e = blockIdx.x * 256 + threadIdx.x;
    if (e >= E) return;
    int d = dst[e];
    int pos = atomicAdd(&cnt[d], 1);
    esrc[off[d] + pos] = src[e];
}

// ---------------------------------------------------------------------------
// MFMA bf16x3 GEMM + fused attention dots.
//   ft[n, h*64+k] = sum_d x[n,d]*W[h,d,k] + b[h,k]   (fp32-accurate via hi/lo)
//   a1[n,h] = ft[n,h,:].al[h,:]+bl[h];  a2 likewise (ar,br)
// grid = (ceil(N/64), H); block = 128 (2 waves); wave tile 32x64.
// LDS: A[row][k] (k contig) and B[n][k] (k contig), row stride 40 ushorts.
// ---------------------------------------------------------------------------
#define LDK 40

__global__ __launch_bounds__(128) void gemm_attn_mfma(
    const float* __restrict__ X, const float* __restrict__ W,
    const float* __restrict__ bias, const float* __restrict__ al,
    const float* __restrict__ bl, const float* __restrict__ ar,
    const float* __restrict__ br, float* __restrict__ FT,
    float* __restrict__ A1, float* __restrict__ A2, int Nn, int D) {
    __shared__ __align__(16) unsigned short Ahi[64 * LDK];
    __shared__ __align__(16) unsigned short Alo[64 * LDK];
    __shared__ __align__(16) unsigned short Bhi[64 * LDK];
    __shared__ __align__(16) unsigned short Blo[64 * LDK];

    int tid = threadIdx.x;
    int h = blockIdx.y, H = gridDim.y, HK = H * 64;
    int n0 = blockIdx.x * 64;
    int wv = tid >> 6, l = tid & 63;
    int lm = l & 15, quad = l >> 4;
    const float* Wh = W + (size_t)h * D * 64;

    f32x4 acc[2][4];
#pragma unroll
    for (int r = 0; r < 2; r++)
#pragma unroll
        for (int c = 0; c < 4; c++) acc[r][c] = (f32x4){0.f, 0.f, 0.f, 0.f};

    // B staging role: n = tid&63 (coalesced along n), khalf = tid>>6
    int bn = tid & 63, bk0 = (tid >> 6) * 16;

    for (int d0 = 0; d0 < D; d0 += 32) {
        // ---- stage A: X tile 64x32 fp32 -> hi/lo bf16 ----
#pragma unroll
        for (int i = 0; i < 4; i++) {
            int idx = tid + i * 128;
            int row = idx >> 3, c4 = idx & 7;
            float4 v = make_float4(0.f, 0.f, 0.f, 0.f);
            if (n0 + row < Nn)
                v = *(const float4*)&X[(size_t)(n0 + row) * D + d0 + c4 * 4];
            float f[4] = {v.x, v.y, v.z, v.w};
            unsigned short hi[4], lo[4];
#pragma unroll
            for (int j = 0; j < 4; j++) {
                hi[j] = bf16_rne(f[j]);
                lo[j] = bf16_rne(f[j] - bf16_tof(hi[j]));
            }
            *(ushort4*)&Ahi[row * LDK + c4 * 4] = make_ushort4(hi[0], hi[1], hi[2], hi[3]);
            *(ushort4*)&Alo[row * LDK + c4 * 4] = make_ushort4(lo[0], lo[1], lo[2], lo[3]);
        }
        // ---- stage B transposed: W tile 32x64 -> Bs[n][k] hi/lo ----
#pragma unroll
        for (int kp = 0; kp < 8; kp++) {
            int k = bk0 + kp * 2;
            float f0 = Wh[(size_t)(d0 + k) * 64 + bn];
            float f1 = Wh[(size_t)(d0 + k + 1) * 64 + bn];
            unsigned short h0 = bf16_rne(f0), h1 = bf16_rne(f1);
            unsigned short l0 = bf16_rne(f0 - bf16_tof(h0));
            unsigned short l1 = bf16_rne(f1 - bf16_tof(h1));
            *(ushort2*)&Bhi[bn * LDK + k] = make_ushort2(h0, h1);
            *(ushort2*)&Blo[bn * LDK + k] = make_ushort2(l0, l1);
        }
        __syncthreads();

        // ---- fragments + MFMA ----
        bf16x8 ah[2], alo2[2], bh[4], blo2[4];
#pragma unroll
        for (int r = 0; r < 2; r++) {
            int row = wv * 32 + r * 16 + lm;
            ah[r] = *(const bf16x8*)&Ahi[row * LDK + quad * 8];
            alo2[r] = *(const bf16x8*)&Alo[row * LDK + quad * 8];
        }
#pragma unroll
        for (int c = 0; c < 4; c++) {
            int n = c * 16 + lm;
            bh[c] = *(const bf16x8*)&Bhi[n * LDK + quad * 8];
            blo2[c] = *(const bf16x8*)&Blo[n * LDK + quad * 8];
        }
#pragma unroll
        for (int r = 0; r < 2; r++)
#pragma unroll
            for (int c = 0; c < 4; c++) {
                acc[r][c] = __builtin_amdgcn_mfma_f32_16x16x32_bf16(ah[r], bh[c], acc[r][c], 0, 0, 0);
                acc[r][c] = __builtin_amdgcn_mfma_f32_16x16x32_bf16(ah[r], blo2[c], acc[r][c], 0, 0, 0);
                acc[r][c] = __builtin_amdgcn_mfma_f32_16x16x32_bf16(alo2[r], bh[c], acc[r][c], 0, 0, 0);
            }
        __syncthreads();
    }

    // ---- epilogue: bias, store FT, fused attn dots ----
    float bj[4], alj[4], arj[4];
#pragma unroll
    for (int c = 0; c < 4; c++) {
        bj[c] = bias[h * 64 + c * 16 + lm];
        alj[c] = al[h * 64 + c * 16 + lm];
        arj[c] = ar[h * 64 + c * 16 + lm];
    }
    float blh = bl[h], brh = br[h];
#pragma unroll
    for (int r = 0; r < 2; r++) {
#pragma unroll
        for (int reg = 0; reg < 4; reg++) {
            int row = n0 + wv * 32 + r * 16 + quad * 4 + reg;
            bool ok = row < Nn;
            float s1 = 0.f, s2 = 0.f;
#pragma unroll
            for (int c = 0; c < 4; c++) {
                float o = acc[r][c][reg] + bj[c];
                s1 += o * alj[c];
                s2 += o * arj[c];
                if (ok) FT[(size_t)row * HK + h * 64 + c * 16 + lm] = o;
            }
#pragma unroll
            for (int d = 1; d < 16; d <<= 1) {
                s1 += __shfl_xor(s1, d);
                s2 += __shfl_xor(s2, d);
            }
            if (ok && lm == 0) {
                A1[(size_t)row * H + h] = s1 + blh;
                A2[(size_t)row * H + h] = s2 + brh;
            }
        }
    }
}

// ---------------------------------------------------------------------------
// Edge softmax + aggregation + ELU, one WAVE per dst node, single pass
// (online softmax), wave-synchronous (no barriers). H=2.
// ---------------------------------------------------------------------------
__global__ __launch_bounds__(256) void edge_agg2_kernel(
    const float* __restrict__ ft, const float* __restrict__ a1,
    const float* __restrict__ a2, const int* __restrict__ off,
    const int* __restrict__ esrc, float* __restrict__ out, int Nn) {
    __shared__ __align__(16) float ws[4][64];
    __shared__ __align__(16) int sjs[4][32];
    int wv = threadIdx.x >> 6, lane = threadIdx.x & 63;
    int n = blockIdx.x * 4 + wv;
    if (n >= Nn) return;
    int o0 = off[n], deg = off[n + 1] - o0;
    int hs = lane >> 5;
    int el = lane & 31;
    if (deg == 0) {
        *(float2*)&out[(size_t)n * 128 + lane * 2] = make_float2(0.f, 0.f);
        return;
    }
    float a1v = a1[(size_t)n * 2 + hs];
    float m = -1e30f, dsum = 0.f;
    float accx = 0.f, accy = 0.f;
    for (int e0 = 0; e0 < deg; e0 += 32) {
        int nE = min(32, deg - e0);
        int sj = 0;
        float s = -1e30f;
        if (el < nE) {
            sj = esrc[o0 + e0 + el];
            float t = a1v + a2[(size_t)sj * 2 + hs];
            s = t > 0.f ? t : NEG_SLOPE * t;
        }
        float cm = s;
#pragma unroll
        for (int d = 1; d < 32; d <<= 1) cm = fmaxf(cm, __shfl_xor(cm, d));
        float nm = fmaxf(m, cm);
        float scale = __expf(m - nm);
        float wgt = (el < nE) ? __expf(s - nm) : 0.f;
        float csum = wgt;
#pragma unroll
        for (int d = 1; d < 32; d <<= 1) csum += __shfl_xor(csum, d);
        dsum = dsum * scale + csum;
        accx *= scale;
        accy *= scale;
        m = nm;
        ws[wv][hs * 32 + el] = wgt;
        if (hs == 0 && el < nE) sjs[wv][el] = sj;
        int j = 0;
        for (; j + 4 <= nE; j += 4) {
            float4 w4 = *(const float4*)&ws[wv][hs * 32 + j];
            int4 s4 = *(const int4*)&sjs[wv][j];
            float2 f0 = *(const float2*)&ft[(size_t)s4.x * 128 + lane * 2];
            float2 f1 = *(const float2*)&ft[(size_t)s4.y * 128 + lane * 2];
            float2 f2 = *(const float2*)&ft[(size_t)s4.z * 128 + lane * 2];
            float2 f3 = *(const float2*)&ft[(size_t)s4.w * 128 + lane * 2];
            accx += w4.x * f0.x + w4.y * f1.x + w4.z * f2.x + w4.w * f3.x;
            accy += w4.x * f0.y + w4.y * f1.y + w4.z * f2.y + w4.w * f3.y;
        }
        for (; j < nE; j++) {
            float w0 = ws[wv][hs * 32 + j];
            int s0 = sjs[wv][j];
            float2 f0 = *(const float2*)&ft[(size_t)s0 * 128 + lane * 2];
            accx += w0 * f0.x;
            accy += w0 * f0.y;
        }
    }
    float rd = 1.f / dsum;
    float rx = accx * rd, ry = accy * rd;
    rx = rx > 0.f ? rx : expm1f(rx);
    ry = ry > 0.f ? ry : expm1f(ry);
    *(float2*)&out[(size_t)n * 128 + lane * 2] = make_float2(rx, ry);
}

__global__ __launch_bounds__(256) void edge_agg1_kernel(
    const float* __restrict__ ft, const float* __restrict__ a1,
    const float* __restrict__ a2, const int* __restrict__ off,
    const int* __restrict__ esrc, float* __restrict__ out, int Nn) {
    __shared__ __align__(16) float ws[4][64];
    __shared__ __align__(16) int sjs[4][64];
    int wv = threadIdx.x >> 6, lane = threadIdx.x & 63;
    int n = blockIdx.x * 4 + wv;
    if (n >= Nn) return;
    int o0 = off[n], deg = off[n + 1] - o0;
    if (deg == 0) {
        out[(size_t)n * 64 + lane] = 0.f;
        return;
    }
    float a1v = a1[n];
    float m = -1e30f, dsum = 0.f, acc = 0.f;
    for (int e0 = 0; e0 < deg; e0 += 64) {
        int nE = min(64, deg - e0);
        int sj = 0;
        float s = -1e30f;
        if (lane < nE) {
            sj = esrc[o0 + e0 + lane];
            float t = a1v + a2[sj];
            s = t > 0.f ? t : NEG_SLOPE * t;
        }
        float cm = s;
#pragma unroll
        for (int d = 1; d < 64; d <<= 1) cm = fmaxf(cm, __shfl_xor(cm, d));
        float nm = fmaxf(m, cm);
        float scale = __expf(m - nm);
        float wgt = (lane < nE) ? __expf(s - nm) : 0.f;
        float csum = wgt;
#pragma unroll
        for (int d = 1; d < 64; d <<= 1) csum += __shfl_xor(csum, d);
        dsum = dsum * scale + csum;
        acc *= scale;
        m = nm;
        ws[wv][lane] = wgt;
        if (lane < nE) sjs[wv][lane] = sj;
        int j = 0;
        for (; j + 4 <= nE; j += 4) {
            float4 w4 = *(const float4*)&ws[wv][j];
            int4 s4 = *(const int4*)&sjs[wv][j];
            float f0 = ft[(size_t)s4.x * 64 + lane];
            float f1 = ft[(size_t)s4.y * 64 + lane];
            float f2 = ft[(size_t)s4.z * 64 + lane];
            float f3 = ft[(size_t)s4.w * 64 + lane];
            acc += w4.x * f0 + w4.y * f1 + w4.z * f2 + w4.w * f3;
        }
        for (; j < nE; j++) {
            acc += ws[wv][j] * ft[(size_t)sjs[wv][j] * 64 + lane];
        }
    }
    float r = acc / dsum;
    out[(size_t)n * 64 + lane] = r > 0.f ? r : expm1f(r);
}

// ---------------------------------------------------------------------------
// launch
// ---------------------------------------------------------------------------
extern "C" void kernel_launch(void* const* d_in, const int* in_sizes, int n_in,
                              void* d_out, int out_size, void* d_ws, size_t ws_size,
                              hipStream_t stream) {
    const float* features = (const float*)d_in[0];
    const int* src = (const int*)d_in[1];
    const int* dst = (const int*)d_in[2];
    const float* W0 = (const float*)d_in[3];
    const float* b0 = (const float*)d_in[4];
    const float* al0 = (const float*)d_in[5];
    const float* bl0 = (const float*)d_in[6];
    const float* ar0 = (const float*)d_in[7];
    const float* br0 = (const float*)d_in[8];
    const float* W1 = (const float*)d_in[9];
    const float* b1 = (const float*)d_in[10];
    const float* al1 = (const float*)d_in[11];
    const float* bl1 = (const float*)d_in[12];
    const float* ar1 = (const float*)d_in[13];
    const float* br1 = (const float*)d_in[14];
    const float* Wf = (const float*)d_in[15];
    const float* bf = (const float*)d_in[16];
    const float* alf = (const float*)d_in[17];
    const float* blf = (const float*)d_in[18];
    const float* arf = (const float*)d_in[19];
    const float* brf = (const float*)d_in[20];

    char* p = (char*)d_ws;
    auto carve = [&](size_t bytes) {
        void* q = (void*)p;
        p += (bytes + 255) & ~(size_t)255;
        return q;
    };
    float* ft = (float*)carve((size_t)NN * 128 * 4);
    float* xbuf = (float*)carve((size_t)NN * 128 * 4);
    float* a1 = (float*)carve((size_t)NN * 2 * 4);
    float* a2 = (float*)carve((size_t)NN * 2 * 4);
    int* off = (int*)carve((size_t)(NN + 1) * 4);
    int* cnt = (int*)carve((size_t)NN * 4);
    int* esrc = (int*)carve((size_t)EE * 4);
    int* aux = (int*)carve(64 * 4);

    const int NB_SCAN = (NN + 1023) / 1024;

    // ---- CSR build ----
    hipMemsetAsync(cnt, 0, (size_t)NN * 4, stream);
    hist_kernel<<<(EE + 255) / 256, 256, 0, stream>>>(dst, cnt, EE);
    scanA_kernel<<<NB_SCAN, 1024, 0, stream>>>(cnt, off, aux, NN);
    scanC_kernel<<<NB_SCAN, 1024, 0, stream>>>(aux, off, NN);
    scatter_kernel<<<(EE + 255) / 256, 256, 0, stream>>>(src, dst, off, cnt, esrc, EE);

    const int gx = (NN + 63) / 64;
    const int gn = (NN + 3) / 4;

    // ---- layer 0: D=256, H=2 ----
    gemm_attn_mfma<<<dim3(gx, 2), 128, 0, stream>>>(features, W0, b0, al0, bl0, ar0,
                                                    br0, ft, a1, a2, NN, DIN);
    edge_agg2_kernel<<<gn, 256, 0, stream>>>(ft, a1, a2, off, esrc, xbuf, NN);

    // ---- layer 1: D=128, H=2 ----
    gemm_attn_mfma<<<dim3(gx, 2), 128, 0, stream>>>(xbuf, W1, b1, al1, bl1, ar1, br1,
                                                    ft, a1, a2, NN, 128);
    edge_agg2_kernel<<<gn, 256, 0, stream>>>(ft, a1, a2, off, esrc, xbuf, NN);

    // ---- final layer: D=128, H=1 ----
    gemm_attn_mfma<<<dim3(gx, 1), 128, 0, stream>>>(xbuf, Wf, bf, alf, blf, arf, brf,
                                                    ft, a1, a2, NN, 128);
    edge_agg1_kernel<<<gn, 256, 0, stream>>>(ft, a1, a2, off, esrc, (float*)d_out, NN);
}